// Round 15
// baseline (1404.318 us; speedup 1.0000x reference)
//
#include <hip/hip_runtime.h>

// Viterbi decode (CRF): B=128, T=4096, L=64.
// Outputs: score[B] (f32), path[B][T] (written as float labels).
constexpr int kB = 128;
constexpr int kT = 4096;
constexpr int kL = 64;
constexpr int kSeg = 64;     // number of backtrace segments
constexpr int kSegLen = 64;  // rows per segment (last segment has 63)
constexpr float kNeg = -10000.0f;

typedef float f32x4 __attribute__((ext_vector_type(4)));

// ---------------- shared reduction (identical in both step paths) -----------
__device__ __forceinline__ float red64(const float (&tr)[kL], const f32x4 (&v)[16],
                                       float f) {
  float m[16];
#pragma unroll
  for (int q = 0; q < 16; ++q) {
    float a0 = tr[4 * q + 0] + v[q].x;
    float a1 = tr[4 * q + 1] + v[q].y;
    float a2 = tr[4 * q + 2] + v[q].z;
    float a3 = tr[4 * q + 3] + v[q].w;
    m[q] = fmaxf(fmaxf(fmaxf(a0, a1), a2), a3);  // v_max3 + v_max
  }
  float g0 = fmaxf(fmaxf(m[0], m[1]), m[2]);     // v_max3_f32 x5
  float g1 = fmaxf(fmaxf(m[3], m[4]), m[5]);
  float g2 = fmaxf(fmaxf(m[6], m[7]), m[8]);
  float g3 = fmaxf(fmaxf(m[9], m[10]), m[11]);
  float g4 = fmaxf(fmaxf(m[12], m[13]), m[14]);
  float h0 = fmaxf(fmaxf(g0, g1), g2);           // v_max3_f32 x2
  float h1 = fmaxf(fmaxf(g3, g4), m[15]);
  return fmaxf(h0, h1) + f;
}

// ---------------- K1 step, fused DS transaction (fast path) -----------------
// ONE asm block: ds_write_b32 + 16x ds_read_b128 (uniform base, offset:imm) +
// s_waitcnt lgkmcnt(0). Unsplittable => all reads in flight: ONE LDS
// round-trip per step. CRITICAL: outputs are "=&v" EARLYCLOBBER — ds_read
// dests receive data asynchronously mid-block, so without & the allocator
// aliased outputs onto [ra]/[dv] (R14: VGPR=76 proves it; absmax=52 was
// returning reads clobbering the address register of later reads).
__device__ __forceinline__ float step_fused(const float (&tr)[kL], int waddr,
                                            int zaddr, float d, float f) {
  f32x4 v[16];
  asm volatile(
      "ds_write_b32 %[wa], %[dv]\n\t"
      "ds_read_b128 %[o0], %[ra] offset:0\n\t"
      "ds_read_b128 %[o1], %[ra] offset:16\n\t"
      "ds_read_b128 %[o2], %[ra] offset:32\n\t"
      "ds_read_b128 %[o3], %[ra] offset:48\n\t"
      "ds_read_b128 %[o4], %[ra] offset:64\n\t"
      "ds_read_b128 %[o5], %[ra] offset:80\n\t"
      "ds_read_b128 %[o6], %[ra] offset:96\n\t"
      "ds_read_b128 %[o7], %[ra] offset:112\n\t"
      "ds_read_b128 %[o8], %[ra] offset:128\n\t"
      "ds_read_b128 %[o9], %[ra] offset:144\n\t"
      "ds_read_b128 %[o10], %[ra] offset:160\n\t"
      "ds_read_b128 %[o11], %[ra] offset:176\n\t"
      "ds_read_b128 %[o12], %[ra] offset:192\n\t"
      "ds_read_b128 %[o13], %[ra] offset:208\n\t"
      "ds_read_b128 %[o14], %[ra] offset:224\n\t"
      "ds_read_b128 %[o15], %[ra] offset:240\n\t"
      "s_waitcnt lgkmcnt(0)"
      : [o0] "=&v"(v[0]), [o1] "=&v"(v[1]), [o2] "=&v"(v[2]), [o3] "=&v"(v[3]),
        [o4] "=&v"(v[4]), [o5] "=&v"(v[5]), [o6] "=&v"(v[6]), [o7] "=&v"(v[7]),
        [o8] "=&v"(v[8]), [o9] "=&v"(v[9]), [o10] "=&v"(v[10]), [o11] "=&v"(v[11]),
        [o12] "=&v"(v[12]), [o13] "=&v"(v[13]), [o14] "=&v"(v[14]), [o15] "=&v"(v[15])
      : [wa] "v"(waddr), [dv] "v"(d), [ra] "v"(zaddr)
      : "memory");
  return red64(tr, v, f);
}

// ---------------- K1 step, plain-C LDS broadcast (exact fallback) -----------
__device__ __forceinline__ float step_ldsC(const float (&tr)[kL], float* dl,
                                           const f32x4* dl4, int i, float d, float f) {
  asm volatile("" ::: "memory");
  dl[i] = d;
  asm volatile("" ::: "memory");
  f32x4 v[16];
#pragma unroll
  for (int q = 0; q < 16; ++q) v[q] = dl4[q];
  __builtin_amdgcn_sched_barrier(0);
  return red64(tr, v, f);
}

__global__ __launch_bounds__(64, 1) void fwd_delta(const float* __restrict__ feats,
                                                   const float* __restrict__ trans,
                                                   float* __restrict__ delta) {
  const int i = threadIdx.x;
  const int b = blockIdx.x;
  const size_t kBL = (size_t)kB * kL;
  float tr[kL];
#pragma unroll
  for (int k = 0; k < kL; k += 4) {
    float4 v = *reinterpret_cast<const float4*>(trans + i * kL + k);
    tr[k] = v.x; tr[k + 1] = v.y; tr[k + 2] = v.z; tr[k + 3] = v.w;
  }
  __shared__ __align__(16) float dl[kL];
  const f32x4* dl4 = reinterpret_cast<const f32x4*>(dl);
  // LDS byte offsets: low 32 bits of the flat pointer (keeps dl allocated).
  const unsigned ldsbase = (unsigned)(uintptr_t)(&dl[0]);
  const int waddr = (int)(ldsbase + 4u * (unsigned)i);
  const int zaddr = (int)ldsbase;

  float d0 = (i == 62) ? 0.0f : kNeg;
  float* drow = delta + (size_t)b * kL + i;  // layout [T][B][L]
  *drow = d0;
  drow += kBL;
  const float* fp = feats + (size_t)b * kT * kL + i;

  // ---- verify: TWO chained fused steps vs two chained C steps, bitwise ----
  // (different values written to LDS each step — catches async/ordering bugs
  // the old single same-value verify missed)
  float fA = fp[64 * 1], fB = fp[64 * 2];
  float dF1 = step_fused(tr, waddr, zaddr, d0, fA);
  float dF2 = step_fused(tr, waddr, zaddr, dF1, fB);
  float dE1 = step_ldsC(tr, dl, dl4, i, d0, fA);
  float dE2 = step_ldsC(tr, dl, dl4, i, dE1, fB);
  const bool ok = __all((__float_as_int(dF1) == __float_as_int(dE1)) &&
                        (__float_as_int(dF2) == __float_as_int(dE2))) != 0;
  *drow = dE1; drow += kBL;   // t=1
  *drow = dE2; drow += kBL;   // t=2
  float d = dE2;

  // steps t=3..4095 remain (4093). Prefetch ring t=3..6; loop 1022x4 = t=3..4090.
  float f0 = fp[64 * 3], f1 = fp[64 * 4], f2 = fp[64 * 5], f3 = fp[64 * 6];
  const float* pf = fp + 64 * 7;

  if (ok) {
    for (int it = 0; it < 1022; ++it) {
      d = step_fused(tr, waddr, zaddr, d, f0); *drow = d; drow += kBL; f0 = pf[0];
      d = step_fused(tr, waddr, zaddr, d, f1); *drow = d; drow += kBL; f1 = pf[64];
      d = step_fused(tr, waddr, zaddr, d, f2); *drow = d; drow += kBL; f2 = pf[128];
      d = step_fused(tr, waddr, zaddr, d, f3); *drow = d; drow += kBL; f3 = pf[192];
      pf += 256;
    }
    float g0 = pf[0];  // t=4095
    d = step_fused(tr, waddr, zaddr, d, f0); *drow = d; drow += kBL;  // 4091
    d = step_fused(tr, waddr, zaddr, d, f1); *drow = d; drow += kBL;  // 4092
    d = step_fused(tr, waddr, zaddr, d, f2); *drow = d; drow += kBL;  // 4093
    d = step_fused(tr, waddr, zaddr, d, f3); *drow = d; drow += kBL;  // 4094
    d = step_fused(tr, waddr, zaddr, d, g0); *drow = d;               // 4095
  } else {
    for (int it = 0; it < 1022; ++it) {
      d = step_ldsC(tr, dl, dl4, i, d, f0); *drow = d; drow += kBL; f0 = pf[0];
      d = step_ldsC(tr, dl, dl4, i, d, f1); *drow = d; drow += kBL; f1 = pf[64];
      d = step_ldsC(tr, dl, dl4, i, d, f2); *drow = d; drow += kBL; f2 = pf[128];
      d = step_ldsC(tr, dl, dl4, i, d, f3); *drow = d; drow += kBL; f3 = pf[192];
      pf += 256;
    }
    float g0 = pf[0];
    d = step_ldsC(tr, dl, dl4, i, d, f0); *drow = d; drow += kBL;
    d = step_ldsC(tr, dl, dl4, i, d, f1); *drow = d; drow += kBL;
    d = step_ldsC(tr, dl, dl4, i, d, f2); *drow = d; drow += kBL;
    d = step_ldsC(tr, dl, dl4, i, d, f3); *drow = d; drow += kBL;
    d = step_ldsC(tr, dl, dl4, i, d, g0); *drow = d;
  }
}

// ---------------- K2: recompute backpointers from stored delta --------------
// row r = t*128 + b; delta layout [T][B][L] makes row base = delta + r*64.
__global__ __launch_bounds__(256) void psi_from_delta(const float* __restrict__ delta,
                                                      const float* __restrict__ trans,
                                                      unsigned char* __restrict__ psi) {
  const int lane = threadIdx.x & 63;
  const int w = __builtin_amdgcn_readfirstlane(blockIdx.x * 4 + (threadIdx.x >> 6));
  float tr[kL];
#pragma unroll
  for (int k = 0; k < kL; k += 4) {
    float4 v = *reinterpret_cast<const float4*>(trans + lane * kL + k);
    tr[k] = v.x; tr[k + 1] = v.y; tr[k + 2] = v.z; tr[k + 3] = v.w;
  }
  const int r0 = w * 8;  // 8 rows per wave; grid sized exactly
  for (int rr = 0; rr < 8; ++rr) {
    const int r = r0 + rr;
    const float4* row4 = reinterpret_cast<const float4*>(delta + (size_t)r * kL);
    float bA = -INFINITY, bBv = -INFINITY;
    int iA = 0, iB = 32;
#pragma unroll
    for (int q = 0; q < 8; ++q) {
      float4 dv = row4[q];
      float c; bool g;
      c = tr[4 * q + 0] + dv.x; g = c > bA; bA = g ? c : bA; iA = g ? 4 * q + 0 : iA;
      c = tr[4 * q + 1] + dv.y; g = c > bA; bA = g ? c : bA; iA = g ? 4 * q + 1 : iA;
      c = tr[4 * q + 2] + dv.z; g = c > bA; bA = g ? c : bA; iA = g ? 4 * q + 2 : iA;
      c = tr[4 * q + 3] + dv.w; g = c > bA; bA = g ? c : bA; iA = g ? 4 * q + 3 : iA;
    }
#pragma unroll
    for (int q = 8; q < 16; ++q) {
      float4 dv = row4[q];
      float c; bool g;
      c = tr[4 * q + 0] + dv.x; g = c > bBv; bBv = g ? c : bBv; iB = g ? 4 * q + 0 : iB;
      c = tr[4 * q + 1] + dv.y; g = c > bBv; bBv = g ? c : bBv; iB = g ? 4 * q + 1 : iB;
      c = tr[4 * q + 2] + dv.z; g = c > bBv; bBv = g ? c : bBv; iB = g ? 4 * q + 2 : iB;
      c = tr[4 * q + 3] + dv.w; g = c > bBv; bBv = g ? c : bBv; iB = g ? 4 * q + 3 : iB;
    }
    bool gm = bBv > bA;  // tie -> lower half (first occurrence)
    psi[(size_t)r * kL + lane] = (unsigned char)(gm ? iB : iA);
  }
}

// ---------------- K3: segment composition (in-place psi -> M) ----------------
__global__ __launch_bounds__(256) void seg_compose(unsigned char* psiM,
                                                   unsigned char* __restrict__ C) {
  const int lane = threadIdx.x & 63;
  const int w = blockIdx.x * 4 + (threadIdx.x >> 6);
  const int s = w >> 7;
  const int b = w & 127;
  const int tstart = s * kSegLen;
  const int tend = (tstart + kSegLen < kT) ? tstart + kSegLen : kT - 1;  // last seg: 4095
  const size_t stride = (size_t)kB * kL;
  size_t off = ((size_t)(tend - 1) * kB + b) * kL + lane;
  int m = lane;
  int v = psiM[off];
  for (int t = tend - 1; t > tstart; --t) {
    int vn = psiM[off - stride];          // prefetch next row
    m = __shfl(v, m, 64);                 // m = psi_row[m]
    psiM[off] = (unsigned char)m;         // M[t][b][e] = path[t] | hyp e
    v = vn;
    off -= stride;
  }
  m = __shfl(v, m, 64);
  psiM[off] = (unsigned char)m;
  C[((size_t)s * kB + b) * kL + lane] = (unsigned char)m;  // composed map
}

// ---------------- K4: score, last label, boundary-label scan ----------------
__global__ __launch_bounds__(64) void score_scan(const float* __restrict__ dfin,
                                                 const unsigned char* __restrict__ C,
                                                 int* __restrict__ E,
                                                 float* __restrict__ out) {
  const int b = blockIdx.x;
  const int i = threadIdx.x;
  float d = dfin[(size_t)b * kL + i];
  float m = d;
#pragma unroll
  for (int off = 32; off; off >>= 1) m = fmaxf(m, __shfl_xor(m, off, 64));
  unsigned long long msk = __ballot(d == m);
  int ll = __ffsll(msk) - 1;  // first (lowest) argmax lane
  if (i == 0) {
    out[b] = m;
    out[kB + (size_t)b * kT + (kT - 1)] = (float)ll;
    int lbl = ll;
    for (int s = kSeg - 1; s >= 0; --s) {
      E[s * kB + b] = lbl;                              // label at t_end(s)
      lbl = C[((size_t)s * kB + b) * kL + lbl];         // -> label at t_start(s)
    }
  }
}

// ---------------- K5: parallel path gather ----------------
__global__ __launch_bounds__(256) void path_fill(const unsigned char* __restrict__ M,
                                                 const int* __restrict__ E,
                                                 float* __restrict__ out) {
  const int n = blockIdx.x * 256 + threadIdx.x;  // n = b*4096 + t
  const int b = n >> 12;
  const int t = n & (kT - 1);
  if (t == kT - 1) return;  // written by score_scan
  const int e = E[(t >> 6) * kB + b];
  const unsigned char lab = M[((size_t)t * kB + b) * kL + e];
  out[kB + (size_t)b * kT + t] = (float)lab;
}

extern "C" void kernel_launch(void* const* d_in, const int* in_sizes, int n_in,
                              void* d_out, int out_size, void* d_ws, size_t ws_size,
                              hipStream_t stream) {
  const float* feats = (const float*)d_in[0];
  const float* trans = (const float*)d_in[1];
  float* out = (float*)d_out;
  char* ws = (char*)d_ws;

  const size_t deltaB = (size_t)kT * kB * kL * 4;   // 134,217,728
  const size_t psiB   = (size_t)kT * kB * kL;       //  33,554,432
  const size_t CBy    = (size_t)kSeg * kB * kL;     //     524,288

  float* delta = (float*)ws;
  unsigned char* psi = (unsigned char*)(ws + deltaB);
  unsigned char* C = (unsigned char*)(ws + deltaB + psiB);
  int* E = (int*)(ws + deltaB + psiB + CBy);
  hipLaunchKernelGGL(fwd_delta, dim3(kB), dim3(64), 0, stream, feats, trans, delta);
  hipLaunchKernelGGL(psi_from_delta, dim3(16380), dim3(256), 0, stream, delta, trans, psi);
  hipLaunchKernelGGL(seg_compose, dim3(2048), dim3(256), 0, stream, psi, C);
  hipLaunchKernelGGL(score_scan, dim3(kB), dim3(64), 0, stream,
                     delta + (size_t)(kT - 1) * kB * kL, C, E, out);
  hipLaunchKernelGGL(path_fill, dim3(2048), dim3(256), 0, stream, psi, E, out);
}

// Round 16
// 1169.757 us; speedup vs baseline: 1.2005x; 1.2005x over previous
//
#include <hip/hip_runtime.h>

// Viterbi decode (CRF): B=128, T=4096, L=64.
// Outputs: score[B] (f32), path[B][T] (written as float labels).
constexpr int kB = 128;
constexpr int kT = 4096;
constexpr int kL = 64;
constexpr int kSeg = 64;     // number of backtrace segments
constexpr int kSegLen = 64;  // rows per segment (last segment has 63)
constexpr float kNeg = -10000.0f;

typedef float f32x4 __attribute__((ext_vector_type(4)));

// ---------------- K1 forward: 2-wave cooperative step -----------------------
// Block = 128 threads (2 waves) per batch. Wave w owns output labels
// [32w,32w+32); lane pair (li, li+32) splits the j-range: h=lane>>5 selects
// j in [32h, 32h+32). Per lane: 8 ds_read_b128 (half the DS traffic of the
// 1-wave design) + 32 adds + tree -> pair-partial. Pair combine is VALU-only:
// (a,b) = v_permlane32_swap(part,part) gives {a[i],b[i]} = {part[i],
// part[i^32]} per lane (whatever the output order, fmaxf(a,b) is the pair
// max — no semantics assumption). delta lives in parity-double-buffered
// dbuf[2][64]; ONE __syncthreads per step orders cross-wave write->read.
// Bitwise-exact: identical IEEE adds tr[o][j]+delta[j]; max order-invariant.
__device__ __forceinline__ float step2w(const float (&tr)[32], const f32x4* dlp,
                                        float fo) {
  f32x4 v[8];
#pragma unroll
  for (int q = 0; q < 8; ++q) v[q] = dlp[q];   // 8x ds_read_b128
  float m[8];
#pragma unroll
  for (int q = 0; q < 8; ++q) {
    float a0 = tr[4 * q + 0] + v[q].x;
    float a1 = tr[4 * q + 1] + v[q].y;
    float a2 = tr[4 * q + 2] + v[q].z;
    float a3 = tr[4 * q + 3] + v[q].w;
    m[q] = fmaxf(fmaxf(fmaxf(a0, a1), a2), a3);  // v_max3 + v_max
  }
  float g0 = fmaxf(fmaxf(m[0], m[1]), m[2]);
  float g1 = fmaxf(fmaxf(m[3], m[4]), m[5]);
  float g2 = fmaxf(m[6], m[7]);
  float part = fmaxf(fmaxf(g0, g1), g2);
  auto w2 = __builtin_amdgcn_permlane32_swap(__float_as_uint(part),
                                             __float_as_uint(part), false, false);
  return fmaxf(__uint_as_float(w2[0]), __uint_as_float(w2[1])) + fo;
}

__global__ __launch_bounds__(128, 1) void fwd_delta(const float* __restrict__ feats,
                                                    const float* __restrict__ trans,
                                                    float* __restrict__ delta) {
  const int tid = threadIdx.x;
  const int w = tid >> 6;          // wave 0/1
  const int lane = tid & 63;
  const int h = lane >> 5;         // j-half
  const int li = lane & 31;
  const int o = 32 * w + li;       // output label owned by this lane pair
  const int b = blockIdx.x;
  const size_t kBL = (size_t)kB * kL;

  // tr[k] = trans[o][32h + k], k=0..31 (contiguous -> float4 loads)
  float tr[32];
#pragma unroll
  for (int k = 0; k < 32; k += 4) {
    float4 v = *reinterpret_cast<const float4*>(trans + o * kL + 32 * h + k);
    tr[k] = v.x; tr[k + 1] = v.y; tr[k + 2] = v.z; tr[k + 3] = v.w;
  }

  __shared__ __align__(16) float dbuf[2][kL];
  const f32x4* dlp0 = reinterpret_cast<const f32x4*>(&dbuf[0][32 * h]);
  const f32x4* dlp1 = reinterpret_cast<const f32x4*>(&dbuf[1][32 * h]);

  // init: t=0 row + dbuf[0]
  if (tid < kL) {
    float dd = (tid == 62) ? 0.0f : kNeg;
    dbuf[0][tid] = dd;
    delta[(size_t)b * kL + tid] = dd;
  }
  __syncthreads();

  const float* fpo = feats + (size_t)b * kT * kL + o;
  float* dro = delta + (size_t)b * kL + o;  // store base; step t at dro[t*kBL]
  // prefetch ring: rows 1..4
  float f0 = fpo[64 * 1], f1 = fpo[64 * 2], f2 = fpo[64 * 3], f3 = fpo[64 * 4];
  const float* pf = fpo + 64 * 5;
  size_t off = kBL;  // t=1

#define STEP(DLP, WBUF, FV)                                                     \
  {                                                                             \
    float dnew = step2w(tr, DLP, FV);                                           \
    if (lane < 32) {                                                            \
      dbuf[WBUF][o] = dnew;                                                     \
      dro[off] = dnew;                                                          \
    }                                                                           \
    off += kBL;                                                                 \
    __syncthreads();                                                            \
  }

  for (int it = 0; it < 1022; ++it) {  // steps t=1..4088
    STEP(dlp0, 1, f0) f0 = pf[0];
    STEP(dlp1, 0, f1) f1 = pf[64];
    STEP(dlp0, 1, f2) f2 = pf[128];
    STEP(dlp1, 0, f3) f3 = pf[192];
    pf += 256;
  }
  // remaining: t=4089..4095 (7 steps); pf -> row 4093
  float g0 = pf[0], g1 = pf[64], g2 = pf[128];
  STEP(dlp0, 1, f0)   // 4089
  STEP(dlp1, 0, f1)   // 4090
  STEP(dlp0, 1, f2)   // 4091
  STEP(dlp1, 0, f3)   // 4092
  STEP(dlp0, 1, g0)   // 4093
  STEP(dlp1, 0, g1)   // 4094
  STEP(dlp0, 1, g2)   // 4095
#undef STEP
}

// ---------------- K2: recompute backpointers from stored delta --------------
// row r = t*128 + b; delta layout [T][B][L] makes row base = delta + r*64.
__global__ __launch_bounds__(256) void psi_from_delta(const float* __restrict__ delta,
                                                      const float* __restrict__ trans,
                                                      unsigned char* __restrict__ psi) {
  const int lane = threadIdx.x & 63;
  const int w = __builtin_amdgcn_readfirstlane(blockIdx.x * 4 + (threadIdx.x >> 6));
  float tr[kL];
#pragma unroll
  for (int k = 0; k < kL; k += 4) {
    float4 v = *reinterpret_cast<const float4*>(trans + lane * kL + k);
    tr[k] = v.x; tr[k + 1] = v.y; tr[k + 2] = v.z; tr[k + 3] = v.w;
  }
  const int r0 = w * 8;  // 8 rows per wave; grid sized exactly
  for (int rr = 0; rr < 8; ++rr) {
    const int r = r0 + rr;
    const float4* row4 = reinterpret_cast<const float4*>(delta + (size_t)r * kL);
    float bA = -INFINITY, bBv = -INFINITY;
    int iA = 0, iB = 32;
#pragma unroll
    for (int q = 0; q < 8; ++q) {
      float4 dv = row4[q];
      float c; bool g;
      c = tr[4 * q + 0] + dv.x; g = c > bA; bA = g ? c : bA; iA = g ? 4 * q + 0 : iA;
      c = tr[4 * q + 1] + dv.y; g = c > bA; bA = g ? c : bA; iA = g ? 4 * q + 1 : iA;
      c = tr[4 * q + 2] + dv.z; g = c > bA; bA = g ? c : bA; iA = g ? 4 * q + 2 : iA;
      c = tr[4 * q + 3] + dv.w; g = c > bA; bA = g ? c : bA; iA = g ? 4 * q + 3 : iA;
    }
#pragma unroll
    for (int q = 8; q < 16; ++q) {
      float4 dv = row4[q];
      float c; bool g;
      c = tr[4 * q + 0] + dv.x; g = c > bBv; bBv = g ? c : bBv; iB = g ? 4 * q + 0 : iB;
      c = tr[4 * q + 1] + dv.y; g = c > bBv; bBv = g ? c : bBv; iB = g ? 4 * q + 1 : iB;
      c = tr[4 * q + 2] + dv.z; g = c > bBv; bBv = g ? c : bBv; iB = g ? 4 * q + 2 : iB;
      c = tr[4 * q + 3] + dv.w; g = c > bBv; bBv = g ? c : bBv; iB = g ? 4 * q + 3 : iB;
    }
    bool gm = bBv > bA;  // tie -> lower half (first occurrence)
    psi[(size_t)r * kL + lane] = (unsigned char)(gm ? iB : iA);
  }
}

// ---------------- K3: segment composition (in-place psi -> M) ----------------
__global__ __launch_bounds__(256) void seg_compose(unsigned char* psiM,
                                                   unsigned char* __restrict__ C) {
  const int lane = threadIdx.x & 63;
  const int w = blockIdx.x * 4 + (threadIdx.x >> 6);
  const int s = w >> 7;
  const int b = w & 127;
  const int tstart = s * kSegLen;
  const int tend = (tstart + kSegLen < kT) ? tstart + kSegLen : kT - 1;  // last seg: 4095
  const size_t stride = (size_t)kB * kL;
  size_t off = ((size_t)(tend - 1) * kB + b) * kL + lane;
  int m = lane;
  int v = psiM[off];
  for (int t = tend - 1; t > tstart; --t) {
    int vn = psiM[off - stride];          // prefetch next row
    m = __shfl(v, m, 64);                 // m = psi_row[m]
    psiM[off] = (unsigned char)m;         // M[t][b][e] = path[t] | hyp e
    v = vn;
    off -= stride;
  }
  m = __shfl(v, m, 64);
  psiM[off] = (unsigned char)m;
  C[((size_t)s * kB + b) * kL + lane] = (unsigned char)m;  // composed map
}

// ---------------- K4: score, last label, boundary-label scan ----------------
__global__ __launch_bounds__(64) void score_scan(const float* __restrict__ dfin,
                                                 const unsigned char* __restrict__ C,
                                                 int* __restrict__ E,
                                                 float* __restrict__ out) {
  const int b = blockIdx.x;
  const int i = threadIdx.x;
  float d = dfin[(size_t)b * kL + i];
  float m = d;
#pragma unroll
  for (int off = 32; off; off >>= 1) m = fmaxf(m, __shfl_xor(m, off, 64));
  unsigned long long msk = __ballot(d == m);
  int ll = __ffsll(msk) - 1;  // first (lowest) argmax lane
  if (i == 0) {
    out[b] = m;
    out[kB + (size_t)b * kT + (kT - 1)] = (float)ll;
    int lbl = ll;
    for (int s = kSeg - 1; s >= 0; --s) {
      E[s * kB + b] = lbl;                              // label at t_end(s)
      lbl = C[((size_t)s * kB + b) * kL + lbl];         // -> label at t_start(s)
    }
  }
}

// ---------------- K5: parallel path gather ----------------
__global__ __launch_bounds__(256) void path_fill(const unsigned char* __restrict__ M,
                                                 const int* __restrict__ E,
                                                 float* __restrict__ out) {
  const int n = blockIdx.x * 256 + threadIdx.x;  // n = b*4096 + t
  const int b = n >> 12;
  const int t = n & (kT - 1);
  if (t == kT - 1) return;  // written by score_scan
  const int e = E[(t >> 6) * kB + b];
  const unsigned char lab = M[((size_t)t * kB + b) * kL + e];
  out[kB + (size_t)b * kT + t] = (float)lab;
}

extern "C" void kernel_launch(void* const* d_in, const int* in_sizes, int n_in,
                              void* d_out, int out_size, void* d_ws, size_t ws_size,
                              hipStream_t stream) {
  const float* feats = (const float*)d_in[0];
  const float* trans = (const float*)d_in[1];
  float* out = (float*)d_out;
  char* ws = (char*)d_ws;

  const size_t deltaB = (size_t)kT * kB * kL * 4;   // 134,217,728
  const size_t psiB   = (size_t)kT * kB * kL;       //  33,554,432
  const size_t CBy    = (size_t)kSeg * kB * kL;     //     524,288

  float* delta = (float*)ws;
  unsigned char* psi = (unsigned char*)(ws + deltaB);
  unsigned char* C = (unsigned char*)(ws + deltaB + psiB);
  int* E = (int*)(ws + deltaB + psiB + CBy);
  hipLaunchKernelGGL(fwd_delta, dim3(kB), dim3(128), 0, stream, feats, trans, delta);
  hipLaunchKernelGGL(psi_from_delta, dim3(16380), dim3(256), 0, stream, delta, trans, psi);
  hipLaunchKernelGGL(seg_compose, dim3(2048), dim3(256), 0, stream, psi, C);
  hipLaunchKernelGGL(score_scan, dim3(kB), dim3(64), 0, stream,
                     delta + (size_t)(kT - 1) * kB * kL, C, E, out);
  hipLaunchKernelGGL(path_fill, dim3(2048), dim3(256), 0, stream, psi, E, out);
}

// Round 17
// 1135.288 us; speedup vs baseline: 1.2370x; 1.0304x over previous
//
#include <hip/hip_runtime.h>

// Viterbi decode (CRF): B=128, T=4096, L=64.
// Outputs: score[B] (f32), path[B][T] (written as float labels).
constexpr int kB = 128;
constexpr int kT = 4096;
constexpr int kL = 64;
constexpr int kSeg = 64;     // number of backtrace segments
constexpr int kSegLen = 64;  // rows per segment (last segment has 63)
constexpr float kNeg = -10000.0f;

typedef float f32x4 __attribute__((ext_vector_type(4)));

// ---------------- K1 forward: 4-wave cooperative step -----------------------
// Block = 256 threads (4 waves) per batch. Wave w owns output labels
// [16w,16w+16); lane quad (li, li+16, li+32, li+48) splits j into quarters:
// q=lane>>4 selects j in [16q,16q+16). Per lane: 4 ds_read_b128 + 16 adds +
// tree -> quarter-partial. Combine 1 (i <-> i^32): permlane32_swap trick —
// (a,b)=swap(part,part); fmaxf(a,b)[i] = max(part[i],part[i^32]) whatever
// the output order (PROVEN exact in R16, absmax 0.0). Combine 2 (i <-> i^16):
// __shfl_xor — semantics guaranteed by HIP. delta parity-double-buffered in
// dbuf[2][64]; ONE __syncthreads per step (R16's proven structure).
// Bitwise-exact: identical IEEE adds tr[o][j]+delta[j]; max order-invariant.
__device__ __forceinline__ float step4w(const float (&tr)[16], const f32x4* dlp,
                                        float fo) {
  f32x4 v[4];
#pragma unroll
  for (int q = 0; q < 4; ++q) v[q] = dlp[q];   // 4x ds_read_b128
  float m[4];
#pragma unroll
  for (int q = 0; q < 4; ++q) {
    float a0 = tr[4 * q + 0] + v[q].x;
    float a1 = tr[4 * q + 1] + v[q].y;
    float a2 = tr[4 * q + 2] + v[q].z;
    float a3 = tr[4 * q + 3] + v[q].w;
    m[q] = fmaxf(fmaxf(fmaxf(a0, a1), a2), a3);  // v_max3 + v_max
  }
  float part = fmaxf(fmaxf(fmaxf(m[0], m[1]), m[2]), m[3]);
  auto w2 = __builtin_amdgcn_permlane32_swap(__float_as_uint(part),
                                             __float_as_uint(part), false, false);
  float m1 = fmaxf(__uint_as_float(w2[0]), __uint_as_float(w2[1]));  // i ^ 32
  float m2 = fmaxf(m1, __shfl_xor(m1, 16, 64));                      // i ^ 16
  return m2 + fo;
}

__global__ __launch_bounds__(256, 1) void fwd_delta(const float* __restrict__ feats,
                                                    const float* __restrict__ trans,
                                                    float* __restrict__ delta) {
  const int tid = threadIdx.x;
  const int w = tid >> 6;          // wave 0..3
  const int lane = tid & 63;
  const int q = lane >> 4;         // j-quarter
  const int li = lane & 15;
  const int o = 16 * w + li;       // output label owned by this lane quad
  const int b = blockIdx.x;
  const size_t kBL = (size_t)kB * kL;

  // tr[k] = trans[o][16q + k], k=0..15 (contiguous -> float4 loads)
  float tr[16];
#pragma unroll
  for (int k = 0; k < 16; k += 4) {
    float4 v = *reinterpret_cast<const float4*>(trans + o * kL + 16 * q + k);
    tr[k] = v.x; tr[k + 1] = v.y; tr[k + 2] = v.z; tr[k + 3] = v.w;
  }

  __shared__ __align__(16) float dbuf[2][kL];
  const f32x4* dlp0 = reinterpret_cast<const f32x4*>(&dbuf[0][16 * q]);
  const f32x4* dlp1 = reinterpret_cast<const f32x4*>(&dbuf[1][16 * q]);

  // init: t=0 row + dbuf[0]
  if (tid < kL) {
    float dd = (tid == 62) ? 0.0f : kNeg;
    dbuf[0][tid] = dd;
    delta[(size_t)b * kL + tid] = dd;
  }
  __syncthreads();

  const float* fpo = feats + (size_t)b * kT * kL + o;
  float* dro = delta + (size_t)b * kL + o;  // store base; step t at dro[t*kBL]
  // prefetch ring: rows 1..4
  float f0 = fpo[64 * 1], f1 = fpo[64 * 2], f2 = fpo[64 * 3], f3 = fpo[64 * 4];
  const float* pf = fpo + 64 * 5;
  size_t off = kBL;  // t=1

#define STEP(DLP, WBUF, FV)                                                     \
  {                                                                             \
    float dnew = step4w(tr, DLP, FV);                                           \
    if (lane < 16) {                                                            \
      dbuf[WBUF][o] = dnew;                                                     \
      dro[off] = dnew;                                                          \
    }                                                                           \
    off += kBL;                                                                 \
    __syncthreads();                                                            \
  }

  for (int it = 0; it < 1022; ++it) {  // steps t=1..4088
    STEP(dlp0, 1, f0) f0 = pf[0];
    STEP(dlp1, 0, f1) f1 = pf[64];
    STEP(dlp0, 1, f2) f2 = pf[128];
    STEP(dlp1, 0, f3) f3 = pf[192];
    pf += 256;
  }
  // remaining: t=4089..4095 (7 steps); pf -> row 4093
  float g0 = pf[0], g1 = pf[64], g2 = pf[128];
  STEP(dlp0, 1, f0)   // 4089
  STEP(dlp1, 0, f1)   // 4090
  STEP(dlp0, 1, f2)   // 4091
  STEP(dlp1, 0, f3)   // 4092
  STEP(dlp0, 1, g0)   // 4093
  STEP(dlp1, 0, g1)   // 4094
  STEP(dlp0, 1, g2)   // 4095
#undef STEP
}

// ---------------- K2: recompute backpointers from stored delta --------------
// row r = t*128 + b; delta layout [T][B][L] makes row base = delta + r*64.
__global__ __launch_bounds__(256) void psi_from_delta(const float* __restrict__ delta,
                                                      const float* __restrict__ trans,
                                                      unsigned char* __restrict__ psi) {
  const int lane = threadIdx.x & 63;
  const int w = __builtin_amdgcn_readfirstlane(blockIdx.x * 4 + (threadIdx.x >> 6));
  float tr[kL];
#pragma unroll
  for (int k = 0; k < kL; k += 4) {
    float4 v = *reinterpret_cast<const float4*>(trans + lane * kL + k);
    tr[k] = v.x; tr[k + 1] = v.y; tr[k + 2] = v.z; tr[k + 3] = v.w;
  }
  const int r0 = w * 8;  // 8 rows per wave; grid sized exactly
  for (int rr = 0; rr < 8; ++rr) {
    const int r = r0 + rr;
    const float4* row4 = reinterpret_cast<const float4*>(delta + (size_t)r * kL);
    float bA = -INFINITY, bBv = -INFINITY;
    int iA = 0, iB = 32;
#pragma unroll
    for (int q = 0; q < 8; ++q) {
      float4 dv = row4[q];
      float c; bool g;
      c = tr[4 * q + 0] + dv.x; g = c > bA; bA = g ? c : bA; iA = g ? 4 * q + 0 : iA;
      c = tr[4 * q + 1] + dv.y; g = c > bA; bA = g ? c : bA; iA = g ? 4 * q + 1 : iA;
      c = tr[4 * q + 2] + dv.z; g = c > bA; bA = g ? c : bA; iA = g ? 4 * q + 2 : iA;
      c = tr[4 * q + 3] + dv.w; g = c > bA; bA = g ? c : bA; iA = g ? 4 * q + 3 : iA;
    }
#pragma unroll
    for (int q = 8; q < 16; ++q) {
      float4 dv = row4[q];
      float c; bool g;
      c = tr[4 * q + 0] + dv.x; g = c > bBv; bBv = g ? c : bBv; iB = g ? 4 * q + 0 : iB;
      c = tr[4 * q + 1] + dv.y; g = c > bBv; bBv = g ? c : bBv; iB = g ? 4 * q + 1 : iB;
      c = tr[4 * q + 2] + dv.z; g = c > bBv; bBv = g ? c : bBv; iB = g ? 4 * q + 2 : iB;
      c = tr[4 * q + 3] + dv.w; g = c > bBv; bBv = g ? c : bBv; iB = g ? 4 * q + 3 : iB;
    }
    bool gm = bBv > bA;  // tie -> lower half (first occurrence)
    psi[(size_t)r * kL + lane] = (unsigned char)(gm ? iB : iA);
  }
}

// ---------------- K3: segment composition (in-place psi -> M) ----------------
__global__ __launch_bounds__(256) void seg_compose(unsigned char* psiM,
                                                   unsigned char* __restrict__ C) {
  const int lane = threadIdx.x & 63;
  const int w = blockIdx.x * 4 + (threadIdx.x >> 6);
  const int s = w >> 7;
  const int b = w & 127;
  const int tstart = s * kSegLen;
  const int tend = (tstart + kSegLen < kT) ? tstart + kSegLen : kT - 1;  // last seg: 4095
  const size_t stride = (size_t)kB * kL;
  size_t off = ((size_t)(tend - 1) * kB + b) * kL + lane;
  int m = lane;
  int v = psiM[off];
  for (int t = tend - 1; t > tstart; --t) {
    int vn = psiM[off - stride];          // prefetch next row
    m = __shfl(v, m, 64);                 // m = psi_row[m]
    psiM[off] = (unsigned char)m;         // M[t][b][e] = path[t] | hyp e
    v = vn;
    off -= stride;
  }
  m = __shfl(v, m, 64);
  psiM[off] = (unsigned char)m;
  C[((size_t)s * kB + b) * kL + lane] = (unsigned char)m;  // composed map
}

// ---------------- K4: score, last label, boundary-label scan ----------------
__global__ __launch_bounds__(64) void score_scan(const float* __restrict__ dfin,
                                                 const unsigned char* __restrict__ C,
                                                 int* __restrict__ E,
                                                 float* __restrict__ out) {
  const int b = blockIdx.x;
  const int i = threadIdx.x;
  float d = dfin[(size_t)b * kL + i];
  float m = d;
#pragma unroll
  for (int off = 32; off; off >>= 1) m = fmaxf(m, __shfl_xor(m, off, 64));
  unsigned long long msk = __ballot(d == m);
  int ll = __ffsll(msk) - 1;  // first (lowest) argmax lane
  if (i == 0) {
    out[b] = m;
    out[kB + (size_t)b * kT + (kT - 1)] = (float)ll;
    int lbl = ll;
    for (int s = kSeg - 1; s >= 0; --s) {
      E[s * kB + b] = lbl;                              // label at t_end(s)
      lbl = C[((size_t)s * kB + b) * kL + lbl];         // -> label at t_start(s)
    }
  }
}

// ---------------- K5: parallel path gather ----------------
__global__ __launch_bounds__(256) void path_fill(const unsigned char* __restrict__ M,
                                                 const int* __restrict__ E,
                                                 float* __restrict__ out) {
  const int n = blockIdx.x * 256 + threadIdx.x;  // n = b*4096 + t
  const int b = n >> 12;
  const int t = n & (kT - 1);
  if (t == kT - 1) return;  // written by score_scan
  const int e = E[(t >> 6) * kB + b];
  const unsigned char lab = M[((size_t)t * kB + b) * kL + e];
  out[kB + (size_t)b * kT + t] = (float)lab;
}

extern "C" void kernel_launch(void* const* d_in, const int* in_sizes, int n_in,
                              void* d_out, int out_size, void* d_ws, size_t ws_size,
                              hipStream_t stream) {
  const float* feats = (const float*)d_in[0];
  const float* trans = (const float*)d_in[1];
  float* out = (float*)d_out;
  char* ws = (char*)d_ws;

  const size_t deltaB = (size_t)kT * kB * kL * 4;   // 134,217,728
  const size_t psiB   = (size_t)kT * kB * kL;       //  33,554,432
  const size_t CBy    = (size_t)kSeg * kB * kL;     //     524,288

  float* delta = (float*)ws;
  unsigned char* psi = (unsigned char*)(ws + deltaB);
  unsigned char* C = (unsigned char*)(ws + deltaB + psiB);
  int* E = (int*)(ws + deltaB + psiB + CBy);
  hipLaunchKernelGGL(fwd_delta, dim3(kB), dim3(256), 0, stream, feats, trans, delta);
  hipLaunchKernelGGL(psi_from_delta, dim3(16380), dim3(256), 0, stream, delta, trans, psi);
  hipLaunchKernelGGL(seg_compose, dim3(2048), dim3(256), 0, stream, psi, C);
  hipLaunchKernelGGL(score_scan, dim3(kB), dim3(64), 0, stream,
                     delta + (size_t)(kT - 1) * kB * kL, C, E, out);
  hipLaunchKernelGGL(path_fill, dim3(2048), dim3(256), 0, stream, psi, E, out);
}